// Round 1
// baseline (161.250 us; speedup 1.0000x reference)
//
#include <hip/hip_runtime.h>

#define D 32

__global__ __launch_bounds__(256, 4)
void gin_fused(const float* __restrict__ X,
               const float* __restrict__ W,
               const int* __restrict__ rp,
               const int* __restrict__ ci,
               float* __restrict__ out,
               int n) {
    __shared__ float Wl[D * D];

    int tid = threadIdx.x;
    // Stage W (32x32 = 1024 floats = 4 KB) into LDS: 256 threads x float4
    {
        const float4* Wv = (const float4*)W;
        float4* Wlv = (float4*)Wl;
        Wlv[tid] = Wv[tid];
    }
    __syncthreads();

    int wave = tid >> 6;        // 0..3
    int lane = tid & 63;
    int row = blockIdx.x * 4 + wave;
    if (row >= n) return;

    int start = rp[row];
    int end   = rp[row + 1];

    int g = lane >> 3;          // edge sub-group 0..7 (8 edges in flight)
    int s = lane & 7;           // float4 slot 0..7 (covers 32 floats)

    float4 acc = make_float4(0.f, 0.f, 0.f, 0.f);
    for (int e = start + g; e < end; e += 8) {
        int c = ci[e];
        const float4 xr = ((const float4*)(X + (size_t)c * D))[s];
        acc.x += xr.x; acc.y += xr.y; acc.z += xr.z; acc.w += xr.w;
    }

    // Reduce across the 8 edge groups: xor over g bits (8, 16, 32)
    #pragma unroll
    for (int off = 8; off < 64; off <<= 1) {
        acc.x += __shfl_xor(acc.x, off, 64);
        acc.y += __shfl_xor(acc.y, off, 64);
        acc.z += __shfl_xor(acc.z, off, 64);
        acc.w += __shfl_xor(acc.w, off, 64);
    }
    // Every lane now holds the aggregated row slice for d in [4*s, 4*s+4)

    // Epilogue: out[row][j] = sum_d acc[d] * W[d][j]; lane j computes one output
    int j = lane & 31;
    float o = 0.f;
    #pragma unroll
    for (int sg = 0; sg < 8; ++sg) {
        float ax = __shfl(acc.x, sg, 64);
        float ay = __shfl(acc.y, sg, 64);
        float az = __shfl(acc.z, sg, 64);
        float aw = __shfl(acc.w, sg, 64);
        int d = 4 * sg;
        o += ax * Wl[(d    ) * D + j];
        o += ay * Wl[(d + 1) * D + j];
        o += az * Wl[(d + 2) * D + j];
        o += aw * Wl[(d + 3) * D + j];
    }
    if (lane < 32) out[(size_t)row * D + j] = o;
}

extern "C" void kernel_launch(void* const* d_in, const int* in_sizes, int n_in,
                              void* d_out, int out_size, void* d_ws, size_t ws_size,
                              hipStream_t stream) {
    const float* X  = (const float*)d_in[0];
    const float* W  = (const float*)d_in[1];
    const int*   rp = (const int*)d_in[2];
    const int*   ci = (const int*)d_in[3];
    float* out = (float*)d_out;

    int n = in_sizes[2] - 1;            // N nodes (row_pointers has N+1)
    int blocks = (n + 3) / 4;           // 4 rows (waves) per block
    hipLaunchKernelGGL(gin_fused, dim3(blocks), dim3(256), 0, stream,
                       X, W, rp, ci, out, n);
}

// Round 2
// 151.399 us; speedup vs baseline: 1.0651x; 1.0651x over previous
//
#include <hip/hip_runtime.h>

#define D 32

__global__ __launch_bounds__(256, 4)
void gin_fused(const float* __restrict__ X,
               const float* __restrict__ W,
               const int* __restrict__ rp,
               const int* __restrict__ ci,
               float* __restrict__ out,
               int n) {
    __shared__ float Wl[D * D];

    int tid = threadIdx.x;
    {
        const float4* Wv = (const float4*)W;
        float4* Wlv = (float4*)Wl;
        Wlv[tid] = Wv[tid];
    }
    __syncthreads();

    int wave = tid >> 6;        // 0..3
    int lane = tid & 63;
    int row = blockIdx.x * 4 + wave;
    if (row >= n) return;

    int start = rp[row];
    int deg   = rp[row + 1] - start;

    int g = lane >> 3;          // edge sub-group 0..7
    int s = lane & 7;           // float4 slot 0..7

    float4 acc = make_float4(0.f, 0.f, 0.f, 0.f);

    for (int cb = 0; cb < deg; cb += 64) {
        int rem = deg - cb;                       // > 0
        int nv  = rem < 64 ? rem : 64;
        // one coalesced load prefetches up to 64 edge indices for this row
        int myci = (lane < nv) ? ci[start + cb + lane] : 0;

        // edges cb+0 .. cb+31: 4 batched gathers per lane (32 in flight/wave)
        {
            float4 x[4]; float m[4];
            #pragma unroll
            for (int it = 0; it < 4; ++it) {
                int l = it * 8 + g;
                int c = __shfl(myci, l, 64);      // invalid lanes -> row 0
                m[it] = (l < rem) ? 1.f : 0.f;
                x[it] = ((const float4*)(X + (size_t)c * D))[s];
            }
            #pragma unroll
            for (int it = 0; it < 4; ++it) {
                acc.x = fmaf(m[it], x[it].x, acc.x);
                acc.y = fmaf(m[it], x[it].y, acc.y);
                acc.z = fmaf(m[it], x[it].z, acc.z);
                acc.w = fmaf(m[it], x[it].w, acc.w);
            }
        }
        if (rem > 32) {   // wave-uniform branch
            float4 x[4]; float m[4];
            #pragma unroll
            for (int it = 0; it < 4; ++it) {
                int l = (it + 4) * 8 + g;
                int c = __shfl(myci, l, 64);
                m[it] = (l < rem) ? 1.f : 0.f;
                x[it] = ((const float4*)(X + (size_t)c * D))[s];
            }
            #pragma unroll
            for (int it = 0; it < 4; ++it) {
                acc.x = fmaf(m[it], x[it].x, acc.x);
                acc.y = fmaf(m[it], x[it].y, acc.y);
                acc.z = fmaf(m[it], x[it].z, acc.z);
                acc.w = fmaf(m[it], x[it].w, acc.w);
            }
        }
    }

    // Reduce across the 8 edge groups (xor over g bits: 8, 16, 32)
    #pragma unroll
    for (int off = 8; off < 64; off <<= 1) {
        acc.x += __shfl_xor(acc.x, off, 64);
        acc.y += __shfl_xor(acc.y, off, 64);
        acc.z += __shfl_xor(acc.z, off, 64);
        acc.w += __shfl_xor(acc.w, off, 64);
    }
    // lane (g,s) now holds aggregated X_prime[row][4s .. 4s+3]

    // Epilogue: out[row][j] = sum_d agg[d] * W[d][j]
    int j = lane & 31;
    float o = 0.f;
    #pragma unroll
    for (int sg = 0; sg < 8; ++sg) {
        float ax = __shfl(acc.x, sg, 64);
        float ay = __shfl(acc.y, sg, 64);
        float az = __shfl(acc.z, sg, 64);
        float aw = __shfl(acc.w, sg, 64);
        int d = 4 * sg;
        o = fmaf(ax, Wl[(d    ) * D + j], o);
        o = fmaf(ay, Wl[(d + 1) * D + j], o);
        o = fmaf(az, Wl[(d + 2) * D + j], o);
        o = fmaf(aw, Wl[(d + 3) * D + j], o);
    }
    if (lane < 32) out[(size_t)row * D + j] = o;
}

extern "C" void kernel_launch(void* const* d_in, const int* in_sizes, int n_in,
                              void* d_out, int out_size, void* d_ws, size_t ws_size,
                              hipStream_t stream) {
    const float* X  = (const float*)d_in[0];
    const float* W  = (const float*)d_in[1];
    const int*   rp = (const int*)d_in[2];
    const int*   ci = (const int*)d_in[3];
    float* out = (float*)d_out;

    int n = in_sizes[2] - 1;            // N nodes
    int blocks = (n + 3) / 4;           // 4 rows (waves) per block
    hipLaunchKernelGGL(gin_fused, dim3(blocks), dim3(256), 0, stream,
                       X, W, rp, ci, out, n);
}